// Round 2
// baseline (649.206 us; speedup 1.0000x reference)
//
#include <hip/hip_runtime.h>
#include <hip/hip_bf16.h>

#define LL 4
#define NN 50000
#define DD 64
#define EE 500000
#define HID 256
#define KDIM 512
#define LN_EPS 1e-5f

typedef __bf16 bf16x8 __attribute__((ext_vector_type(8)));
typedef float f32x4 __attribute__((ext_vector_type(4)));

__device__ __forceinline__ void async16(const void* g, void* l) {
    __builtin_amdgcn_global_load_lds(
        (const __attribute__((address_space(1))) void*)g,
        (__attribute__((address_space(3))) void*)l, 16, 0, 0);
}

// ---------- kernel 1: t[l,n,d] = bf16( tanh( imp_l * h[l,n,d] ) ) ----------
__global__ void tanh_conv(const float* __restrict__ h, __bf16* __restrict__ t) {
    int i = (blockIdx.x * 256 + threadIdx.x) * 8;          // 12.8M elems, 8/thread
    int l = i / (NN * DD);
    float imp = (float)(l + 1) * 0.1f;
    const float4* p = (const float4*)(h + i);
    float4 a = p[0];
    float4 b = p[1];
    bf16x8 r;
    r[0] = (__bf16)tanhf(imp * a.x);
    r[1] = (__bf16)tanhf(imp * a.y);
    r[2] = (__bf16)tanhf(imp * a.z);
    r[3] = (__bf16)tanhf(imp * a.w);
    r[4] = (__bf16)tanhf(imp * b.x);
    r[5] = (__bf16)tanhf(imp * b.y);
    r[6] = (__bf16)tanhf(imp * b.z);
    r[7] = (__bf16)tanhf(imp * b.w);
    *(bf16x8*)(t + i) = r;
}

// ---------- kernel 2: W1 (256x512 f32) -> bf16, layout [kc][q][h][8] ----------
// element (h, k) with k = kc*32 + q*8 + j  ->  w1c[((kc*4+q)*256 + h)*8 + j]
__global__ void w1_conv(const float* __restrict__ w1, __bf16* __restrict__ o) {
    int t = blockIdx.x * 256 + threadIdx.x;                 // 4096 threads
    int kc = t >> 8;
    int h  = t & 255;
    const float4* p = (const float4*)(w1 + h * KDIM + kc * 32);
    #pragma unroll
    for (int qq = 0; qq < 4; ++qq) {
        float4 va = p[2 * qq];
        float4 vb = p[2 * qq + 1];
        bf16x8 r;
        r[0] = (__bf16)va.x; r[1] = (__bf16)va.y; r[2] = (__bf16)va.z; r[3] = (__bf16)va.w;
        r[4] = (__bf16)vb.x; r[5] = (__bf16)vb.y; r[6] = (__bf16)vb.z; r[7] = (__bf16)vb.w;
        *(bf16x8*)(o + ((size_t)(kc * 4 + qq) * 256 + h) * 8) = r;
    }
}

// ---------- kernel 3: gather + GEMM + LN + ReLU + dot ----------
// WG = 256 threads (4 waves). 128 edges/WG; each wave owns 32 edges (2 m-tiles)
// x 256 hid (16 nt tiles). A-frags read directly from global (tb, L3-resident).
// B double-buffered in LDS via global_load_lds; 1 barrier per K-chunk.
__global__ __launch_bounds__(256, 3)
void edge_mlp(const __bf16* __restrict__ tb, const __bf16* __restrict__ w1c,
              const int* __restrict__ src, const int* __restrict__ dst,
              const float* __restrict__ b1, const float* __restrict__ w3,
              const float* __restrict__ b3, const float* __restrict__ gamma,
              const float* __restrict__ beta, float* __restrict__ out) {
    __shared__ __bf16 B_lds[2 * 8192];   // 2 x 16 KB, layout [q(4)][h(256)][8]
    __shared__ float eb[4 * 256];        // b1 | gamma | beta | w3

    const int tid  = threadIdx.x;
    const int wave = tid >> 6;
    const int lane = tid & 63;
    const int q    = lane >> 4;
    const int c    = lane & 15;

    eb[tid]       = b1[tid];
    eb[256 + tid] = gamma[tid];
    eb[512 + tid] = beta[tid];
    eb[768 + tid] = w3[tid];

    const int e_base = blockIdx.x * 128 + wave * 32;
    const int e0c = e_base + c;
    const int e1c = e_base + 16 + c;
    // per-lane node byte... element offsets into a (NN x 64) layer plane
    const int os0 = ((e0c < EE) ? src[e0c] : 0) * DD;
    const int od0 = ((e0c < EE) ? dst[e0c] : 0) * DD;
    const int os1 = ((e1c < EE) ? src[e1c] : 0) * DD;
    const int od1 = ((e1c < EE) ? dst[e1c] : 0) * DD;

    // stage B chunk 0 via async DMA (linear 16 KB copy)
    #pragma unroll
    for (int j = 0; j < 4; ++j)
        async16(w1c + j * 2048 + tid * 8, &B_lds[j * 2048 + tid * 8]);

    // prefetch A chunk 0 (kc=0: layer 0, src half, c0=0)
    uint4 a0 = *(const uint4*)(tb + os0 + q * 8);
    uint4 a1 = *(const uint4*)(tb + os1 + q * 8);

    f32x4 acc0[16], acc1[16];
    #pragma unroll
    for (int i = 0; i < 16; ++i) {
        acc0[i] = (f32x4){0.f, 0.f, 0.f, 0.f};
        acc1[i] = (f32x4){0.f, 0.f, 0.f, 0.f};
    }

    __syncthreads();   // B chunk 0 + A regs ready

    int pc = 0;
    #pragma unroll
    for (int kc = 0; kc < 16; ++kc) {
        // start DMA of next B chunk into the other buffer
        if (kc < 15) {
            const __bf16* s = w1c + (kc + 1) * 8192;
            const int boff = (pc ^ 1) * 8192;
            #pragma unroll
            for (int j = 0; j < 4; ++j)
                async16(s + j * 2048 + tid * 8, &B_lds[boff + j * 2048 + tid * 8]);
        }
        // prefetch next A chunk into registers
        uint4 an0, an1;
        if (kc < 15) {
            const int kcn = kc + 1;
            const int l   = kcn >> 2;
            const int c0  = (kcn & 1) * 32;
            const int half = (kcn >> 1) & 1;
            const __bf16* base = tb + l * (NN * DD) + c0 + q * 8;
            an0 = *(const uint4*)(base + (half ? od0 : os0));
            an1 = *(const uint4*)(base + (half ? od1 : os1));
        }
        // MFMA on current buffer
        bf16x8 af0 = __builtin_bit_cast(bf16x8, a0);
        bf16x8 af1 = __builtin_bit_cast(bf16x8, a1);
        const __bf16* Bp = &B_lds[pc * 8192 + q * 2048 + c * 8];
        #pragma unroll
        for (int nt = 0; nt < 16; ++nt) {
            bf16x8 bf = *(const bf16x8*)(Bp + nt * 128);
            acc0[nt] = __builtin_amdgcn_mfma_f32_16x16x32_bf16(af0, bf, acc0[nt], 0, 0, 0);
            acc1[nt] = __builtin_amdgcn_mfma_f32_16x16x32_bf16(af1, bf, acc1[nt], 0, 0, 0);
        }
        __syncthreads();   // drains DMA + A prefetch; all waves done reading pc
        a0 = an0; a1 = an1; pc ^= 1;
    }

    // ---- epilogue: LN + ReLU + dot(w3), per tile, all within the wave ----
    // C/D layout: col(hid%16) = lane&15, row(edge%16) = q*4 + reg.
    #pragma unroll
    for (int t = 0; t < 2; ++t) {
        f32x4* acc = t ? acc1 : acc0;
        float sum[4] = {0.f, 0.f, 0.f, 0.f};
        float sq[4]  = {0.f, 0.f, 0.f, 0.f};
        #pragma unroll
        for (int nt = 0; nt < 16; ++nt) {
            float bb = eb[nt * 16 + c];
            #pragma unroll
            for (int r = 0; r < 4; ++r) {
                float v = acc[nt][r] + bb;
                sum[r] += v;
                sq[r]   = fmaf(v, v, sq[r]);
            }
        }
        #pragma unroll
        for (int m = 1; m < 16; m <<= 1) {
            #pragma unroll
            for (int r = 0; r < 4; ++r) {
                sum[r] += __shfl_xor(sum[r], m);
                sq[r]  += __shfl_xor(sq[r],  m);
            }
        }
        float mu[4], rs[4];
        #pragma unroll
        for (int r = 0; r < 4; ++r) {
            mu[r] = sum[r] * (1.0f / 256.0f);
            float var = sq[r] * (1.0f / 256.0f) - mu[r] * mu[r];
            rs[r] = rsqrtf(var + LN_EPS);
        }
        float dot[4] = {0.f, 0.f, 0.f, 0.f};
        #pragma unroll
        for (int nt = 0; nt < 16; ++nt) {
            int hh   = nt * 16 + c;
            float bb = eb[hh];
            float g  = eb[256 + hh];
            float bt = eb[512 + hh];
            float w  = eb[768 + hh];
            #pragma unroll
            for (int r = 0; r < 4; ++r) {
                float v = acc[nt][r] + bb;
                float y = (v - mu[r]) * rs[r] * g + bt;
                y = fmaxf(y, 0.0f);
                dot[r] = fmaf(y, w, dot[r]);
            }
        }
        #pragma unroll
        for (int m = 1; m < 16; m <<= 1) {
            #pragma unroll
            for (int r = 0; r < 4; ++r) dot[r] += __shfl_xor(dot[r], m);
        }
        if (c == 0) {
            float b3v = b3[0];
            #pragma unroll
            for (int r = 0; r < 4; ++r) {
                int e = e_base + t * 16 + q * 4 + r;
                if (e < EE) out[e] = dot[r] + b3v;
            }
        }
    }
}

extern "C" void kernel_launch(void* const* d_in, const int* in_sizes, int n_in,
                              void* d_out, int out_size, void* d_ws, size_t ws_size,
                              hipStream_t stream) {
    const float* h_all  = (const float*)d_in[0];
    const int*   src    = (const int*)  d_in[1];
    const int*   dst    = (const int*)  d_in[2];
    const float* W1     = (const float*)d_in[3];
    const float* b1     = (const float*)d_in[4];
    const float* W3     = (const float*)d_in[5];
    const float* b3     = (const float*)d_in[6];
    const float* gamma2 = (const float*)d_in[7];
    const float* beta2  = (const float*)d_in[8];
    float* out = (float*)d_out;

    __bf16* tb  = (__bf16*)d_ws;                       // 12.8M bf16 = 25.6 MB
    __bf16* w1c = tb + (size_t)LL * NN * DD;           // 131072 bf16 = 256 KB

    tanh_conv<<<6250, 256, 0, stream>>>(h_all, tb);
    w1_conv<<<16, 256, 0, stream>>>(W1, w1c);
    edge_mlp<<<(EE + 127) / 128, 256, 0, stream>>>(tb, w1c, src, dst,
                                                   b1, W3, b3, gamma2, beta2, out);
}

// Round 3
// 311.903 us; speedup vs baseline: 2.0814x; 2.0814x over previous
//
#include <hip/hip_runtime.h>
#include <hip/hip_bf16.h>

#define LL 4
#define NN 50000
#define DD 64
#define EE 500000
#define HID 256
#define KDIM 512
#define LN_EPS 1e-5f

typedef __bf16 bf16x8 __attribute__((ext_vector_type(8)));
typedef float f32x4 __attribute__((ext_vector_type(4)));

__device__ __forceinline__ void async16(const void* g, void* l) {
    __builtin_amdgcn_global_load_lds(
        (const __attribute__((address_space(1))) void*)g,
        (__attribute__((address_space(3))) void*)l, 16, 0, 0);
}

// ---------- kernel 1: t[l,n,d] = bf16( tanh( imp_l * h[l,n,d] ) ) ----------
__global__ void tanh_conv(const float* __restrict__ h, __bf16* __restrict__ t) {
    int i = (blockIdx.x * 256 + threadIdx.x) * 8;          // 12.8M elems, 8/thread
    int l = i / (NN * DD);
    float imp = (float)(l + 1) * 0.1f;
    const float4* p = (const float4*)(h + i);
    float4 a = p[0];
    float4 b = p[1];
    bf16x8 r;
    r[0] = (__bf16)tanhf(imp * a.x);
    r[1] = (__bf16)tanhf(imp * a.y);
    r[2] = (__bf16)tanhf(imp * a.z);
    r[3] = (__bf16)tanhf(imp * a.w);
    r[4] = (__bf16)tanhf(imp * b.x);
    r[5] = (__bf16)tanhf(imp * b.y);
    r[6] = (__bf16)tanhf(imp * b.z);
    r[7] = (__bf16)tanhf(imp * b.w);
    *(bf16x8*)(t + i) = r;
}

// ---------- kernel 2: W1 (256x512 f32) -> bf16, layout [kc][q][h][8] ----------
// element (h, k) with k = kc*32 + q*8 + j  ->  w1c[((kc*4+q)*256 + h)*8 + j]
__global__ void w1_conv(const float* __restrict__ w1, __bf16* __restrict__ o) {
    int t = blockIdx.x * 256 + threadIdx.x;                 // 4096 threads
    int kc = t >> 8;
    int h  = t & 255;
    const float4* p = (const float4*)(w1 + h * KDIM + kc * 32);
    #pragma unroll
    for (int qq = 0; qq < 4; ++qq) {
        float4 va = p[2 * qq];
        float4 vb = p[2 * qq + 1];
        bf16x8 r;
        r[0] = (__bf16)va.x; r[1] = (__bf16)va.y; r[2] = (__bf16)va.z; r[3] = (__bf16)va.w;
        r[4] = (__bf16)vb.x; r[5] = (__bf16)vb.y; r[6] = (__bf16)vb.z; r[7] = (__bf16)vb.w;
        *(bf16x8*)(o + ((size_t)(kc * 4 + qq) * 256 + h) * 8) = r;
    }
}

// ---------- epilogue macro: LN + ReLU + dot(w3) for one 16-edge acc tile ----
// C/D layout: col(hid%16) = lane&15 (c), row(edge%16) = q*4 + reg.
// Macro (not function/lambda) so no pointer to acc arrays is ever formed ->
// accumulators stay in the unified VGPR/AGPR file (R2's pointer-select
// spilled both arrays to scratch: WRITE_SIZE 2MB->1.3GB, VGPR 84).
#define EPILOGUE(ACC, T)                                                      \
    do {                                                                      \
        float sum[4] = {0.f, 0.f, 0.f, 0.f};                                  \
        float sq[4]  = {0.f, 0.f, 0.f, 0.f};                                  \
        _Pragma("unroll")                                                     \
        for (int nt = 0; nt < 16; ++nt) {                                     \
            float bb = eb[nt * 16 + c];                                       \
            _Pragma("unroll")                                                 \
            for (int r = 0; r < 4; ++r) {                                     \
                float v = ACC[nt][r] + bb;                                    \
                sum[r] += v;                                                  \
                sq[r]   = fmaf(v, v, sq[r]);                                  \
            }                                                                 \
        }                                                                     \
        _Pragma("unroll")                                                     \
        for (int m = 1; m < 16; m <<= 1) {                                    \
            _Pragma("unroll")                                                 \
            for (int r = 0; r < 4; ++r) {                                     \
                sum[r] += __shfl_xor(sum[r], m);                              \
                sq[r]  += __shfl_xor(sq[r],  m);                              \
            }                                                                 \
        }                                                                     \
        float mu[4], rs[4];                                                   \
        _Pragma("unroll")                                                     \
        for (int r = 0; r < 4; ++r) {                                         \
            mu[r] = sum[r] * (1.0f / 256.0f);                                 \
            float var = sq[r] * (1.0f / 256.0f) - mu[r] * mu[r];              \
            rs[r] = rsqrtf(var + LN_EPS);                                     \
        }                                                                     \
        float dot[4] = {0.f, 0.f, 0.f, 0.f};                                  \
        _Pragma("unroll")                                                     \
        for (int nt = 0; nt < 16; ++nt) {                                     \
            int hh   = nt * 16 + c;                                           \
            float bb = eb[hh];                                                \
            float g  = eb[256 + hh];                                          \
            float bt = eb[512 + hh];                                          \
            float w  = eb[768 + hh];                                          \
            _Pragma("unroll")                                                 \
            for (int r = 0; r < 4; ++r) {                                     \
                float v = ACC[nt][r] + bb;                                    \
                float y = (v - mu[r]) * rs[r] * g + bt;                       \
                y = fmaxf(y, 0.0f);                                           \
                dot[r] = fmaf(y, w, dot[r]);                                  \
            }                                                                 \
        }                                                                     \
        _Pragma("unroll")                                                     \
        for (int m = 1; m < 16; m <<= 1) {                                    \
            _Pragma("unroll")                                                 \
            for (int r = 0; r < 4; ++r) dot[r] += __shfl_xor(dot[r], m);      \
        }                                                                     \
        if (c == 0) {                                                         \
            float b3v = b3[0];                                                \
            _Pragma("unroll")                                                 \
            for (int r = 0; r < 4; ++r) {                                     \
                int e = e_base + (T) * 16 + q * 4 + r;                        \
                if (e < EE) out[e] = dot[r] + b3v;                            \
            }                                                                 \
        }                                                                     \
    } while (0)

// ---------- kernel 3: gather + GEMM + LN + ReLU + dot ----------
// WG = 256 threads (4 waves). 128 edges/WG; each wave owns 32 edges (2 m-tiles)
// x 256 hid (16 nt tiles). A-frags read directly from global (tb, L3-resident).
// B double-buffered in LDS via global_load_lds; 1 barrier per K-chunk.
__global__ __launch_bounds__(256, 2)
void edge_mlp(const __bf16* __restrict__ tb, const __bf16* __restrict__ w1c,
              const int* __restrict__ src, const int* __restrict__ dst,
              const float* __restrict__ b1, const float* __restrict__ w3,
              const float* __restrict__ b3, const float* __restrict__ gamma,
              const float* __restrict__ beta, float* __restrict__ out) {
    __shared__ __bf16 B_lds[2 * 8192];   // 2 x 16 KB, layout [q(4)][h(256)][8]
    __shared__ float eb[4 * 256];        // b1 | gamma | beta | w3

    const int tid  = threadIdx.x;
    const int wave = tid >> 6;
    const int lane = tid & 63;
    const int q    = lane >> 4;
    const int c    = lane & 15;

    eb[tid]       = b1[tid];
    eb[256 + tid] = gamma[tid];
    eb[512 + tid] = beta[tid];
    eb[768 + tid] = w3[tid];

    const int e_base = blockIdx.x * 128 + wave * 32;
    const int e0c = e_base + c;
    const int e1c = e_base + 16 + c;
    // per-lane node element offsets into a (NN x 64) layer plane
    const int os0 = ((e0c < EE) ? src[e0c] : 0) * DD;
    const int od0 = ((e0c < EE) ? dst[e0c] : 0) * DD;
    const int os1 = ((e1c < EE) ? src[e1c] : 0) * DD;
    const int od1 = ((e1c < EE) ? dst[e1c] : 0) * DD;

    // stage B chunk 0 via async DMA (linear 16 KB copy)
    #pragma unroll
    for (int j = 0; j < 4; ++j)
        async16(w1c + j * 2048 + tid * 8, &B_lds[j * 2048 + tid * 8]);

    // prefetch A chunk 0 (kc=0: layer 0, src half, c0=0)
    uint4 a0 = *(const uint4*)(tb + os0 + q * 8);
    uint4 a1 = *(const uint4*)(tb + os1 + q * 8);

    f32x4 acc0[16], acc1[16];
    #pragma unroll
    for (int i = 0; i < 16; ++i) {
        acc0[i] = (f32x4){0.f, 0.f, 0.f, 0.f};
        acc1[i] = (f32x4){0.f, 0.f, 0.f, 0.f};
    }

    __syncthreads();   // B chunk 0 + A regs ready

    int pc = 0;
    #pragma unroll
    for (int kc = 0; kc < 16; ++kc) {
        // start DMA of next B chunk into the other buffer
        if (kc < 15) {
            const __bf16* s = w1c + (kc + 1) * 8192;
            const int boff = (pc ^ 1) * 8192;
            #pragma unroll
            for (int j = 0; j < 4; ++j)
                async16(s + j * 2048 + tid * 8, &B_lds[boff + j * 2048 + tid * 8]);
        }
        // prefetch next A chunk into registers
        uint4 an0, an1;
        if (kc < 15) {
            const int kcn = kc + 1;
            const int l   = kcn >> 2;
            const int c0  = (kcn & 1) * 32;
            const int half = (kcn >> 1) & 1;
            const __bf16* base = tb + l * (NN * DD) + c0 + q * 8;
            an0 = *(const uint4*)(base + (half ? od0 : os0));
            an1 = *(const uint4*)(base + (half ? od1 : os1));
        }
        // MFMA on current buffer
        bf16x8 af0 = __builtin_bit_cast(bf16x8, a0);
        bf16x8 af1 = __builtin_bit_cast(bf16x8, a1);
        const __bf16* Bp = &B_lds[pc * 8192 + q * 2048 + c * 8];
        #pragma unroll
        for (int nt = 0; nt < 16; ++nt) {
            bf16x8 bf = *(const bf16x8*)(Bp + nt * 128);
            acc0[nt] = __builtin_amdgcn_mfma_f32_16x16x32_bf16(af0, bf, acc0[nt], 0, 0, 0);
            acc1[nt] = __builtin_amdgcn_mfma_f32_16x16x32_bf16(af1, bf, acc1[nt], 0, 0, 0);
        }
        __syncthreads();   // drains DMA + A prefetch; all waves done reading pc
        a0 = an0; a1 = an1; pc ^= 1;
    }

    EPILOGUE(acc0, 0);
    EPILOGUE(acc1, 1);
}

extern "C" void kernel_launch(void* const* d_in, const int* in_sizes, int n_in,
                              void* d_out, int out_size, void* d_ws, size_t ws_size,
                              hipStream_t stream) {
    const float* h_all  = (const float*)d_in[0];
    const int*   src    = (const int*)  d_in[1];
    const int*   dst    = (const int*)  d_in[2];
    const float* W1     = (const float*)d_in[3];
    const float* b1     = (const float*)d_in[4];
    const float* W3     = (const float*)d_in[5];
    const float* b3     = (const float*)d_in[6];
    const float* gamma2 = (const float*)d_in[7];
    const float* beta2  = (const float*)d_in[8];
    float* out = (float*)d_out;

    __bf16* tb  = (__bf16*)d_ws;                       // 12.8M bf16 = 25.6 MB
    __bf16* w1c = tb + (size_t)LL * NN * DD;           // 131072 bf16 = 256 KB

    tanh_conv<<<6250, 256, 0, stream>>>(h_all, tb);
    w1_conv<<<16, 256, 0, stream>>>(W1, w1c);
    edge_mlp<<<(EE + 127) / 128, 256, 0, stream>>>(tb, w1c, src, dst,
                                                   b1, W3, b3, gamma2, beta2, out);
}